// Round 4
// baseline (603.311 us; speedup 1.0000x reference)
//
#include <hip/hip_runtime.h>
#include <hip/hip_bf16.h>
#include <cstdint>

typedef __attribute__((ext_vector_type(8))) __bf16 bf16x8;
typedef __attribute__((ext_vector_type(4))) float f32x4;
typedef unsigned short u16;

#define DEV static __device__ __forceinline__

constexpr float ATT_SCALE = 0.125f;   // 64^-0.5 (module uses dimHead=64)
constexpr float LN_EPS = 1e-3f;

DEV void gload16(const void* g, void* l) {
  __builtin_amdgcn_global_load_lds((__attribute__((address_space(1))) void*)(g),
                                   (__attribute__((address_space(3))) void*)(l),
                                   16, 0, 0);
}

DEV u16 f2b(float f) { __hip_bfloat16 h = __float2bfloat16(f); return __builtin_bit_cast(u16, h); }

// ---------------- weight transpose + convert ----------------
template<int PERM>
__global__ __launch_bounds__(256)
void k_transpose(const float* __restrict__ in, __hip_bfloat16* __restrict__ out,
                 int R, int C) {
  __shared__ float t[64][65];
  int d0 = blockIdx.x * 64, k0 = blockIdx.y * 64;
  int tid = threadIdx.x;
  int c64 = tid & 63, r4 = tid >> 6;
#pragma unroll
  for (int i = 0; i < 16; i++) {
    int kr = i * 4 + r4;
    t[c64][kr] = in[(size_t)(k0 + kr) * C + d0 + c64];
  }
  __syncthreads();
#pragma unroll
  for (int i = 0; i < 16; i++) {
    int dr = i * 4 + r4;
    int d = d0 + dr;
    int jp = PERM ? ((d % 3) * 1024 + ((d / 3) & 7) * 128 + (d / 24)) : d;
    out[(size_t)jp * R + k0 + c64] = __float2bfloat16(t[dr][c64]);
  }
}

// ---------------- LayerNorm (f32 in -> bf16 out) ----------------
__global__ __launch_bounds__(256)
void k_ln(const float* __restrict__ in, const float* __restrict__ g,
          const float* __restrict__ b, __hip_bfloat16* __restrict__ out) {
  int row = blockIdx.x, tid = threadIdx.x;
  const float4* in4 = (const float4*)(in + (size_t)row * 1024);
  float4 v = in4[tid];
  float s = v.x + v.y + v.z + v.w;
  float ss = v.x * v.x + v.y * v.y + v.z * v.z + v.w * v.w;
#pragma unroll
  for (int off = 32; off; off >>= 1) { s += __shfl_down(s, off); ss += __shfl_down(ss, off); }
  __shared__ float red[8];
  int w = tid >> 6, lane = tid & 63;
  if (lane == 0) { red[w] = s; red[4 + w] = ss; }
  __syncthreads();
  if (tid == 0) {
    float S = red[0] + red[1] + red[2] + red[3];
    float SS = red[4] + red[5] + red[6] + red[7];
    float mu = S * (1.f / 1024.f);
    float var = SS * (1.f / 1024.f) - mu * mu;
    red[0] = mu; red[1] = rsqrtf(var + LN_EPS);
  }
  __syncthreads();
  float mu = red[0], rs = red[1];
  int c = tid * 4;
  ushort4 o;
  o.x = f2b((v.x - mu) * rs * g[c + 0] + b[c + 0]);
  o.y = f2b((v.y - mu) * rs * g[c + 1] + b[c + 1]);
  o.z = f2b((v.z - mu) * rs * g[c + 2] + b[c + 2]);
  o.w = f2b((v.w - mu) * rs * g[c + 3] + b[c + 3]);
  ((ushort4*)((u16*)out + (size_t)row * 1024))[tid] = o;
}

// ================= NEW GEMM: 256xBN tile, BK=32, 3-slot ring, counted vmcnt ==
// C[M,N] = A[M,K] * Bt[N,K]^T.  8 waves (512 thr): wr=wid>>2 (2), wc=wid&3 (4).
// Per-wave out: 128 x (BN/4).  LDS slot: A[256][32] + B[BN][32], XOR-swizzled
// (elem col ^= ((row>>1)&3)<<3; same involution on stage-source and ds_read).
// Pipeline: iter t stages tile t+2 into slot freed at t-1; s_waitcnt vmcnt(L)
// (L = loads/tile, never 0 mid-loop) + raw s_barrier publishes tile t+1.
// MODE 0: relu(+b3 permuted) -> scatter q/k [BH,N,C], vT [BH,C,N]
// MODE 1: relu(+b1) -> bf16 out [M,Nout]
template<int NI, int MODE>
__global__ __launch_bounds__(512, NI == 2 ? 4 : 2)
void k_gemm2(const __hip_bfloat16* __restrict__ A,
             const __hip_bfloat16* __restrict__ Bt,
             const float* __restrict__ bias,
             __hip_bfloat16* __restrict__ outQ,
             __hip_bfloat16* __restrict__ outK,
             __hip_bfloat16* __restrict__ outV,
             int K, int Nout) {
  constexpr int BN = NI * 64;
  constexpr int ASZ = 256 * 32;          // elems
  constexpr int BSZ = BN * 32;
  constexpr int SLOT = ASZ + BSZ;
  __shared__ alignas(16) __hip_bfloat16 lds[3 * SLOT];
  int tid = threadIdx.x, wid = tid >> 6, lane = tid & 63;
  int wr = wid >> 2, wc = wid & 3, lr = lane >> 4, lc = lane & 15;
  int nwg = gridDim.x;
  int wg = ((int)blockIdx.x & 7) * (nwg >> 3) + ((int)blockIdx.x >> 3);  // XCD swizzle
  int mtile = wg & 31, ntile = wg >> 5;   // M=8192 fixed -> 32 mtiles, mtile-fast
  int m0 = mtile * 256, n0 = ntile * BN;
  int NT = K >> 5;

  int sw = ((tid >> 3) & 3) << 3;        // stage-source col XOR (row = tid>>2)
  const __hip_bfloat16* aS = A + (size_t)(m0 + (tid >> 2)) * K + (((tid & 3) * 8) ^ sw);
  const __hip_bfloat16* bS = Bt + (size_t)(n0 + (tid >> 2)) * K + (((tid & 3) * 8) ^ sw);
  const size_t K128 = (size_t)128 * K;

  f32x4 acc[8][NI] = {};

  auto STAGE = [&](int t, int slot) {
    char* s = (char*)(lds + slot * SLOT);
    const __hip_bfloat16* ap = aS + t * 32;
    gload16(ap, s + tid * 16);
    gload16(ap + K128, s + tid * 16 + 8192);
    const __hip_bfloat16* bp = bS + t * 32;
    gload16(bp, s + tid * 16 + 16384);
    if constexpr (NI == 4) gload16(bp + K128, s + tid * 16 + 24576);
  };

  STAGE(0, 0); STAGE(1, 1);
  if constexpr (NI == 2) asm volatile("s_waitcnt vmcnt(3)" ::: "memory");
  else                   asm volatile("s_waitcnt vmcnt(4)" ::: "memory");
  __builtin_amdgcn_s_barrier();
  asm volatile("" ::: "memory");

  int axor = ((lc >> 1) & 3) << 3;       // read-side col XOR (row = ..+lc)
  int s_cur = 0;
  for (int t = 0; t < NT; ++t) {
    if (t + 2 < NT) { int s2 = s_cur + 2; if (s2 >= 3) s2 -= 3; STAGE(t + 2, s2); }
    const __hip_bfloat16* As = lds + s_cur * SLOT;
    const __hip_bfloat16* Bs = As + ASZ;
    bf16x8 af[8], bfr[NI];
#pragma unroll
    for (int mi = 0; mi < 8; mi++)
      af[mi] = *(const bf16x8*)(As + (wr * 128 + mi * 16 + lc) * 32 + ((lr * 8) ^ axor));
#pragma unroll
    for (int ni = 0; ni < NI; ni++)
      bfr[ni] = *(const bf16x8*)(Bs + (wc * (BN / 4) + ni * 16 + lc) * 32 + ((lr * 8) ^ axor));
    __builtin_amdgcn_s_setprio(1);
#pragma unroll
    for (int mi = 0; mi < 8; mi++)
#pragma unroll
      for (int ni = 0; ni < NI; ni++)
        acc[mi][ni] = __builtin_amdgcn_mfma_f32_16x16x32_bf16(af[mi], bfr[ni], acc[mi][ni], 0, 0, 0);
    __builtin_amdgcn_s_setprio(0);
    if (t + 2 < NT) {
      if constexpr (NI == 2) asm volatile("s_waitcnt vmcnt(3)" ::: "memory");
      else                   asm volatile("s_waitcnt vmcnt(4)" ::: "memory");
    } else {
      asm volatile("s_waitcnt vmcnt(0)" ::: "memory");
    }
    asm volatile("" ::: "memory");
    __builtin_amdgcn_s_barrier();
    asm volatile("" ::: "memory");
    s_cur = s_cur + 1; if (s_cur >= 3) s_cur = 0;
  }

#pragma unroll
  for (int mi = 0; mi < 8; mi++) {
#pragma unroll
    for (int ni = 0; ni < NI; ni++) {
      int jp = n0 + wc * (BN / 4) + ni * 16 + lc;
#pragma unroll
      for (int r = 0; r < 4; r++) {
        int m = m0 + wr * 128 + mi * 16 + lr * 4 + r;
        float v = acc[mi][ni][r];
        if (MODE == 0) {
          int i = jp >> 10, h = (jp >> 7) & 7, c = jp & 127;
          v += bias[c * 24 + h * 3 + i];
          v = fmaxf(v, 0.f);
          __hip_bfloat16 bv = __float2bfloat16(v);
          int b_ = m >> 11, n = m & 2047;
          size_t bh = (size_t)(b_ * 8 + h);
          if (i == 0)      outQ[(bh * 2048 + n) * 128 + c] = bv;
          else if (i == 1) outK[(bh * 2048 + n) * 128 + c] = bv;
          else             outV[(bh * 128 + c) * 2048 + n] = bv;
        } else {
          v += bias[jp];
          v = fmaxf(v, 0.f);
          outQ[(size_t)m * Nout + jp] = __float2bfloat16(v);
        }
      }
    }
  }
}

// ---------------- old GEMM (kept for MLP2: +b2 + resid -> f32 out) ----------
__global__ __launch_bounds__(256, 2)
void k_gemm(const __hip_bfloat16* __restrict__ A,
            const __hip_bfloat16* __restrict__ Bt,
            const float* __restrict__ bias,
            const float* __restrict__ resid,
            float* __restrict__ outF,
            int K, int Nout) {
  __shared__ alignas(16) __hip_bfloat16 Asm[128 * 32];
  __shared__ alignas(16) __hip_bfloat16 Bsm[128 * 32];
  int tid = threadIdx.x, w = tid >> 6, lane = tid & 63;
  int wr = w >> 1, wc = w & 1;
  int lr = lane >> 4, lc = lane & 15;
  int m0 = blockIdx.y * 128, n0 = blockIdx.x * 128;
  f32x4 acc[4][4] = {};
  const __hip_bfloat16* aG = A + (size_t)(m0 + (tid >> 2)) * K + (tid & 3) * 8;
  const __hip_bfloat16* bG = Bt + (size_t)(n0 + (tid >> 2)) * K + (tid & 3) * 8;
  char* aB = (char*)Asm + w * 1024;
  char* bB = (char*)Bsm + w * 1024;
  for (int k0 = 0; k0 < K; k0 += 32) {
    gload16(aG + k0, aB);
    gload16(aG + (size_t)64 * K + k0, aB + 4096);
    gload16(bG + k0, bB);
    gload16(bG + (size_t)64 * K + k0, bB + 4096);
    __syncthreads();
    bf16x8 af[4], bfr[4];
#pragma unroll
    for (int mi = 0; mi < 4; mi++)
      af[mi] = *(const bf16x8*)(Asm + (wr * 64 + mi * 16 + lc) * 32 + lr * 8);
#pragma unroll
    for (int ni = 0; ni < 4; ni++)
      bfr[ni] = *(const bf16x8*)(Bsm + (wc * 64 + ni * 16 + lc) * 32 + lr * 8);
#pragma unroll
    for (int mi = 0; mi < 4; mi++)
#pragma unroll
      for (int ni = 0; ni < 4; ni++)
        acc[mi][ni] = __builtin_amdgcn_mfma_f32_16x16x32_bf16(af[mi], bfr[ni], acc[mi][ni], 0, 0, 0);
    __syncthreads();
  }
#pragma unroll
  for (int mi = 0; mi < 4; mi++) {
#pragma unroll
    for (int ni = 0; ni < 4; ni++) {
      int jp = n0 + wc * 64 + ni * 16 + lc;
#pragma unroll
      for (int r = 0; r < 4; r++) {
        int m = m0 + wr * 64 + mi * 16 + lr * 4 + r;
        float v = acc[mi][ni][r] + bias[jp] + resid[(size_t)m * Nout + jp];
        outF[(size_t)m * Nout + jp] = v;
      }
    }
  }
}

// ---------------- flash attention + residual (double-buffered K/V) ----------
// q,k: [BH=32][N=2048][C=128] bf16 ; vT: [BH][C][N] bf16 ; x,y: [B,N,1024] f32
__global__ __launch_bounds__(256, 2)
void k_attn(const __hip_bfloat16* __restrict__ qb,
            const __hip_bfloat16* __restrict__ kb,
            const __hip_bfloat16* __restrict__ vtb,
            const float* __restrict__ x,
            float* __restrict__ y) {
  __shared__ alignas(16) __hip_bfloat16 Kl[2][64 * 128];   // [kv][c] swizzled
  __shared__ alignas(16) __hip_bfloat16 Vl[2][128 * 64];   // [c][kv] swizzled
  __shared__ alignas(16) __hip_bfloat16 Pl[4 * 16 * 72];
  int tid = threadIdx.x, w = tid >> 6, lane = tid & 63;
  int lr = lane >> 4, lc = lane & 15;
  int sxz = (lc & 7) << 3;                 // read-side XOR (elems)
  int qt = blockIdx.x, bh = blockIdx.y;
  int b_ = bh >> 3, h = bh & 7;
  int q0 = qt * 64;
  size_t bhN = (size_t)bh * 2048;

  bf16x8 qf[4];
#pragma unroll
  for (int ks = 0; ks < 4; ks++)
    qf[ks] = *(const bf16x8*)(qb + (bhN + q0 + w * 16 + lc) * 128 + ks * 32 + lr * 8);

  f32x4 oacc[8] = {};
  float mrun[4], lrun[4];
#pragma unroll
  for (int r = 0; r < 4; r++) { mrun[r] = -1e30f; lrun[r] = 0.f; }

  int krow = tid >> 4;
  int kcol = ((tid & 15) * 8) ^ ((krow & 7) << 3);
  const __hip_bfloat16* kG = kb + (bhN + krow) * 128 + kcol;
  int vrow = tid >> 3;
  int vcol = ((tid & 7) * 8) ^ ((vrow & 7) << 3);
  const __hip_bfloat16* vG = vtb + ((size_t)bh * 128 + vrow) * 2048 + vcol;

  auto STAGEKV = [&](int kv0, int buf) {
    char* kB = (char*)(&Kl[buf][0]) + w * 1024;
    char* vB = (char*)(&Vl[buf][0]) + w * 1024;
#pragma unroll
    for (int p = 0; p < 4; p++)
      gload16(kG + (size_t)(kv0 + p * 16) * 128, kB + p * 4096);
#pragma unroll
    for (int p = 0; p < 4; p++)
      gload16(vG + kv0 + (size_t)p * 32 * 2048, vB + p * 4096);
  };

  STAGEKV(0, 0);
  __syncthreads();

  for (int it = 0; it < 32; ++it) {
    int buf = it & 1;
    if (it < 31) STAGEKV((it + 1) * 64, buf ^ 1);
    const __hip_bfloat16* Kb = &Kl[buf][0];
    const __hip_bfloat16* Vb = &Vl[buf][0];

    // S = Q K^T : 16 q rows x 64 kv cols per wave
    f32x4 sf[4] = {};
    __builtin_amdgcn_s_setprio(1);
#pragma unroll
    for (int ks = 0; ks < 4; ks++) {
      bf16x8 kfr[4];
#pragma unroll
      for (int ni = 0; ni < 4; ni++)
        kfr[ni] = *(const bf16x8*)(Kb + (ni * 16 + lc) * 128 + ((ks * 32 + lr * 8) ^ sxz));
#pragma unroll
      for (int ni = 0; ni < 4; ni++)
        sf[ni] = __builtin_amdgcn_mfma_f32_16x16x32_bf16(qf[ks], kfr[ni], sf[ni], 0, 0, 0);
    }
    __builtin_amdgcn_s_setprio(0);

    // online softmax (rows lr*4+r, reduce across 16-lane groups)
#pragma unroll
    for (int r = 0; r < 4; r++) {
      float tmax = fmaxf(fmaxf(sf[0][r], sf[1][r]), fmaxf(sf[2][r], sf[3][r]));
#pragma unroll
      for (int off = 1; off < 16; off <<= 1) tmax = fmaxf(tmax, __shfl_xor(tmax, off, 16));
      tmax *= ATT_SCALE;
      float mnew = fmaxf(mrun[r], tmax);
      float alpha = __expf(mrun[r] - mnew);
      mrun[r] = mnew;
      float rs = 0.f;
#pragma unroll
      for (int ni = 0; ni < 4; ni++) {
        float p = __expf(sf[ni][r] * ATT_SCALE - mnew);
        sf[ni][r] = p;
        rs += p;
      }
#pragma unroll
      for (int off = 1; off < 16; off <<= 1) rs += __shfl_xor(rs, off, 16);
      lrun[r] = lrun[r] * alpha + rs;
#pragma unroll
      for (int nc = 0; nc < 8; nc++) oacc[nc][r] *= alpha;
    }

    // P -> LDS (per-wave region, 72-elem padded rows: conflict-free)
#pragma unroll
    for (int ni = 0; ni < 4; ni++)
#pragma unroll
      for (int r = 0; r < 4; r++)
        Pl[w * 1152 + (lr * 4 + r) * 72 + ni * 16 + lc] = __float2bfloat16(sf[ni][r]);
    asm volatile("s_waitcnt lgkmcnt(0)" ::: "memory");

    // O += P V
    __builtin_amdgcn_s_setprio(1);
#pragma unroll
    for (int ks2 = 0; ks2 < 2; ks2++) {
      bf16x8 pa = *(const bf16x8*)(Pl + w * 1152 + lc * 72 + ks2 * 32 + lr * 8);
#pragma unroll
      for (int nc = 0; nc < 8; nc++) {
        bf16x8 vf = *(const bf16x8*)(Vb + (nc * 16 + lc) * 64 + ((ks2 * 32 + lr * 8) ^ sxz));
        oacc[nc] = __builtin_amdgcn_mfma_f32_16x16x32_bf16(pa, vf, oacc[nc], 0, 0, 0);
      }
    }
    __builtin_amdgcn_s_setprio(0);
    __syncthreads();   // drains this iter's prefetch (issued a full compute ago)
  }

  // epilogue: y = O/l + x
#pragma unroll
  for (int r = 0; r < 4; r++) {
    int n = q0 + w * 16 + lr * 4 + r;
    float inv = 1.f / lrun[r];
    size_t base = ((size_t)(b_ * 2048 + n)) * 1024 + h * 128;
#pragma unroll
    for (int nc = 0; nc < 8; nc++) {
      int c = nc * 16 + lc;
      y[base + c] = oacc[nc][r] * inv + x[base + c];
    }
  }
}

// ---------------- launch ----------------
extern "C" void kernel_launch(void* const* d_in, const int* in_sizes, int n_in,
                              void* d_out, int out_size, void* d_ws, size_t ws_size,
                              hipStream_t stream) {
  const float* x   = (const float*)d_in[0];
  const float* lng = (const float*)d_in[1];
  const float* lnb = (const float*)d_in[2];
  const float* w3  = (const float*)d_in[3];
  const float* b3  = (const float*)d_in[4];
  const float* w1  = (const float*)d_in[5];
  const float* b1  = (const float*)d_in[6];
  const float* w2  = (const float*)d_in[7];
  const float* b2  = (const float*)d_in[8];
  float* out = (float*)d_out;

  constexpr size_t M = 8192;
  __hip_bfloat16* w3t  = (__hip_bfloat16*)d_ws;                 // [3072][1024]
  __hip_bfloat16* w1t  = w3t + (size_t)3072 * 1024;             // [4096][1024]
  __hip_bfloat16* w2t  = w1t + (size_t)4096 * 1024;             // [1024][4096]
  __hip_bfloat16* xln  = w2t + (size_t)4096 * 1024;             // [8192][1024] (also y1)
  __hip_bfloat16* qb   = xln + M * 1024;                        // [32][2048][128]
  __hip_bfloat16* kbuf = qb + M * 1024;
  __hip_bfloat16* vtb  = kbuf + M * 1024;
  __hip_bfloat16* hmid = qb;                                    // overlay: [8192][4096]

  k_transpose<1><<<dim3(48, 16), 256, 0, stream>>>(w3, w3t, 1024, 3072);
  k_transpose<0><<<dim3(64, 16), 256, 0, stream>>>(w1, w1t, 1024, 4096);
  k_transpose<0><<<dim3(16, 64), 256, 0, stream>>>(w2, w2t, 4096, 1024);
  k_ln<<<dim3(M), 256, 0, stream>>>(x, lng, lnb, xln);
  // QKV: BN=128 -> 24 ntiles x 32 mtiles = 768 blocks
  k_gemm2<2, 0><<<dim3(768), 512, 0, stream>>>(xln, w3t, b3, qb, kbuf, vtb, 1024, 3072);
  k_attn<<<dim3(32, 32), 256, 0, stream>>>(qb, kbuf, vtb, x, out);
  k_ln<<<dim3(M), 256, 0, stream>>>(out, lng, lnb, xln);
  // MLP1: BN=256 -> 16 ntiles x 32 mtiles = 512 blocks
  k_gemm2<4, 1><<<dim3(512), 512, 0, stream>>>(xln, w1t, b1, hmid, nullptr, nullptr, 1024, 4096);
  // MLP2 (K=4096) stays on the old template
  k_gemm<<<dim3(8, 64), 256, 0, stream>>>(hmid, w2t, b2, out, out, 4096, 1024);
}

// Round 6
// 540.067 us; speedup vs baseline: 1.1171x; 1.1171x over previous
//
#include <hip/hip_runtime.h>
#include <hip/hip_bf16.h>
#include <cstdint>

typedef __attribute__((ext_vector_type(8))) __bf16 bf16x8;
typedef __attribute__((ext_vector_type(4))) float f32x4;
typedef unsigned short u16;

#define DEV static __device__ __forceinline__

constexpr float ATT_SCALE = 0.125f;   // 64^-0.5 (module uses dimHead=64)
constexpr float LN_EPS = 1e-3f;

DEV void gload16(const void* g, void* l) {
  __builtin_amdgcn_global_load_lds((__attribute__((address_space(1))) void*)(g),
                                   (__attribute__((address_space(3))) void*)(l),
                                   16, 0, 0);
}

DEV u16 f2b(float f) { __hip_bfloat16 h = __float2bfloat16(f); return __builtin_bit_cast(u16, h); }

// ---------------- weight transpose + convert ----------------
template<int PERM>
__global__ __launch_bounds__(256)
void k_transpose(const float* __restrict__ in, __hip_bfloat16* __restrict__ out,
                 int R, int C) {
  __shared__ float t[64][65];
  int d0 = blockIdx.x * 64, k0 = blockIdx.y * 64;
  int tid = threadIdx.x;
  int c64 = tid & 63, r4 = tid >> 6;
#pragma unroll
  for (int i = 0; i < 16; i++) {
    int kr = i * 4 + r4;
    t[c64][kr] = in[(size_t)(k0 + kr) * C + d0 + c64];
  }
  __syncthreads();
#pragma unroll
  for (int i = 0; i < 16; i++) {
    int dr = i * 4 + r4;
    int d = d0 + dr;
    int jp = PERM ? ((d % 3) * 1024 + ((d / 3) & 7) * 128 + (d / 24)) : d;
    out[(size_t)jp * R + k0 + c64] = __float2bfloat16(t[dr][c64]);
  }
}

// ---------------- LayerNorm (f32 in -> bf16 out) ----------------
__global__ __launch_bounds__(256)
void k_ln(const float* __restrict__ in, const float* __restrict__ g,
          const float* __restrict__ b, __hip_bfloat16* __restrict__ out) {
  int row = blockIdx.x, tid = threadIdx.x;
  const float4* in4 = (const float4*)(in + (size_t)row * 1024);
  float4 v = in4[tid];
  float s = v.x + v.y + v.z + v.w;
  float ss = v.x * v.x + v.y * v.y + v.z * v.z + v.w * v.w;
#pragma unroll
  for (int off = 32; off; off >>= 1) { s += __shfl_down(s, off); ss += __shfl_down(ss, off); }
  __shared__ float red[8];
  int w = tid >> 6, lane = tid & 63;
  if (lane == 0) { red[w] = s; red[4 + w] = ss; }
  __syncthreads();
  if (tid == 0) {
    float S = red[0] + red[1] + red[2] + red[3];
    float SS = red[4] + red[5] + red[6] + red[7];
    float mu = S * (1.f / 1024.f);
    float var = SS * (1.f / 1024.f) - mu * mu;
    red[0] = mu; red[1] = rsqrtf(var + LN_EPS);
  }
  __syncthreads();
  float mu = red[0], rs = red[1];
  int c = tid * 4;
  ushort4 o;
  o.x = f2b((v.x - mu) * rs * g[c + 0] + b[c + 0]);
  o.y = f2b((v.y - mu) * rs * g[c + 1] + b[c + 1]);
  o.z = f2b((v.z - mu) * rs * g[c + 2] + b[c + 2]);
  o.w = f2b((v.w - mu) * rs * g[c + 3] + b[c + 3]);
  ((ushort4*)((u16*)out + (size_t)row * 1024))[tid] = o;
}

// ---------------- GEMM: C[M,N] = A[M,K] * Bt[N,K]^T (R3-proven m97-style) ----
template<int MODE>
__global__ __launch_bounds__(256, 2)
void k_gemm(const __hip_bfloat16* __restrict__ A,
            const __hip_bfloat16* __restrict__ Bt,
            const float* __restrict__ bias,
            const float* __restrict__ resid,
            float* __restrict__ outF,
            __hip_bfloat16* __restrict__ outQ,
            __hip_bfloat16* __restrict__ outK,
            __hip_bfloat16* __restrict__ outV,
            int K, int Nout) {
  __shared__ alignas(16) __hip_bfloat16 Asm[128 * 32];
  __shared__ alignas(16) __hip_bfloat16 Bsm[128 * 32];
  int tid = threadIdx.x, w = tid >> 6, lane = tid & 63;
  int wr = w >> 1, wc = w & 1;
  int lr = lane >> 4, lc = lane & 15;
  int m0 = blockIdx.y * 128, n0 = blockIdx.x * 128;
  f32x4 acc[4][4] = {};
  const __hip_bfloat16* aG = A + (size_t)(m0 + (tid >> 2)) * K + (tid & 3) * 8;
  const __hip_bfloat16* bG = Bt + (size_t)(n0 + (tid >> 2)) * K + (tid & 3) * 8;
  char* aB = (char*)Asm + w * 1024;
  char* bB = (char*)Bsm + w * 1024;
  for (int k0 = 0; k0 < K; k0 += 32) {
    gload16(aG + k0, aB);
    gload16(aG + (size_t)64 * K + k0, aB + 4096);
    gload16(bG + k0, bB);
    gload16(bG + (size_t)64 * K + k0, bB + 4096);
    __syncthreads();
    bf16x8 af[4], bfr[4];
#pragma unroll
    for (int mi = 0; mi < 4; mi++)
      af[mi] = *(const bf16x8*)(Asm + (wr * 64 + mi * 16 + lc) * 32 + lr * 8);
#pragma unroll
    for (int ni = 0; ni < 4; ni++)
      bfr[ni] = *(const bf16x8*)(Bsm + (wc * 64 + ni * 16 + lc) * 32 + lr * 8);
#pragma unroll
    for (int mi = 0; mi < 4; mi++)
#pragma unroll
      for (int ni = 0; ni < 4; ni++)
        acc[mi][ni] = __builtin_amdgcn_mfma_f32_16x16x32_bf16(af[mi], bfr[ni], acc[mi][ni], 0, 0, 0);
    __syncthreads();
  }
#pragma unroll
  for (int mi = 0; mi < 4; mi++) {
#pragma unroll
    for (int ni = 0; ni < 4; ni++) {
      int jp = n0 + wc * 64 + ni * 16 + lc;
#pragma unroll
      for (int r = 0; r < 4; r++) {
        int m = m0 + wr * 64 + mi * 16 + lr * 4 + r;
        float v = acc[mi][ni][r];
        if (MODE == 0) {
          int i = jp >> 10, h = (jp >> 7) & 7, c = jp & 127;
          v += bias[c * 24 + h * 3 + i];
          v = fmaxf(v, 0.f);
          __hip_bfloat16 bv = __float2bfloat16(v);
          int b_ = m >> 11, n = m & 2047;
          size_t bh = (size_t)(b_ * 8 + h);
          if (i == 0)      outQ[(bh * 2048 + n) * 128 + c] = bv;
          else if (i == 1) outK[(bh * 2048 + n) * 128 + c] = bv;
          else             outV[(bh * 128 + c) * 2048 + n] = bv;
        } else if (MODE == 1) {
          v += bias[jp];
          v = fmaxf(v, 0.f);
          outQ[(size_t)m * Nout + jp] = __float2bfloat16(v);
        } else {
          v += bias[jp] + resid[(size_t)m * Nout + jp];
          outF[(size_t)m * Nout + jp] = v;
        }
      }
    }
  }
}

// ---------------- flash attention + residual ----------------
// 512 thr (8 waves), QBLK=128 (16 q-rows/wave), KVBLK=64.
// K double-buffered (prefetch t+1 at iter top, published by end-of-iter
// __syncthreads). V single-buffered: staged at iter top, hidden under
// QK^T+softmax; each wave drains its OWN loads with counted vmcnt(2), then a
// raw s_barrier publishes all waves' V slices before PV (K prefetch stays in
// flight across it).  LDS 66KB -> 2 blocks/CU = 16 waves/CU.
__global__ __launch_bounds__(512, 4)
void k_attn(const __hip_bfloat16* __restrict__ qb,
            const __hip_bfloat16* __restrict__ kb,
            const __hip_bfloat16* __restrict__ vtb,
            const float* __restrict__ x,
            float* __restrict__ y) {
  __shared__ alignas(16) __hip_bfloat16 Kl[2][64 * 128];   // [kv][c] swizzled
  __shared__ alignas(16) __hip_bfloat16 Vl[128 * 64];      // [c][kv] swizzled
  __shared__ alignas(16) __hip_bfloat16 Pl[8 * 16 * 72];
  int tid = threadIdx.x, w = tid >> 6, lane = tid & 63;
  int lr = lane >> 4, lc = lane & 15;
  int sxz = (lc & 7) << 3;                 // read-side XOR (elems)
  int qt = blockIdx.x, bh = blockIdx.y;
  int b_ = bh >> 3, h = bh & 7;
  int q0 = qt * 128;
  size_t bhN = (size_t)bh * 2048;

  // Q fragment: wave owns q rows [q0 + w*16, +16)
  bf16x8 qf[4];
#pragma unroll
  for (int ks = 0; ks < 4; ks++)
    qf[ks] = *(const bf16x8*)(qb + (bhN + q0 + w * 16 + lc) * 128 + ks * 32 + lr * 8);

  f32x4 oacc[8] = {};
  float mrun[4], lrun[4];
#pragma unroll
  for (int r = 0; r < 4; r++) { mrun[r] = -1e30f; lrun[r] = 0.f; }

  // staging addresses: linear LDS dest, source column pre-swizzled by row&7
  int krow = tid >> 4;                                   // 0..31 (+p*32)
  int kcol = ((tid & 15) * 8) ^ ((krow & 7) << 3);
  const __hip_bfloat16* kG = kb + (bhN + krow) * 128 + kcol;
  int vrow = tid >> 3;                                   // 0..63 (+p*64)
  int vcol = ((tid & 7) * 8) ^ ((vrow & 7) << 3);
  const __hip_bfloat16* vG = vtb + ((size_t)bh * 128 + vrow) * 2048 + vcol;

  auto STAGE_K = [&](int kv0, int buf) {
    char* kB = (char*)(&Kl[buf][0]) + w * 1024;
#pragma unroll
    for (int p = 0; p < 2; p++)
      gload16(kG + (size_t)(kv0 + p * 32) * 128, kB + p * 8192);
  };
  auto STAGE_V = [&](int kv0) {
    char* vB = (char*)(&Vl[0]) + w * 1024;
#pragma unroll
    for (int p = 0; p < 2; p++)
      gload16(vG + kv0 + (size_t)p * 64 * 2048, vB + p * 8192);
  };

  STAGE_V(0);
  STAGE_K(0, 0);
  asm volatile("s_waitcnt vmcnt(0)" ::: "memory");
  __syncthreads();

  for (int it = 0; it < 32; ++it) {
    int buf = it & 1;
    if (it > 0) STAGE_V(it * 64);            // into single V buffer (post-barrier legal)
    if (it < 31) STAGE_K((it + 1) * 64, buf ^ 1);
    const __hip_bfloat16* Kb = &Kl[buf][0];

    // S = Q K^T : 16 q rows x 64 kv cols per wave
    f32x4 sf[4] = {};
    __builtin_amdgcn_s_setprio(1);
#pragma unroll
    for (int ks = 0; ks < 4; ks++) {
      bf16x8 kfr[4];
#pragma unroll
      for (int ni = 0; ni < 4; ni++)
        kfr[ni] = *(const bf16x8*)(Kb + (ni * 16 + lc) * 128 + ((ks * 32 + lr * 8) ^ sxz));
#pragma unroll
      for (int ni = 0; ni < 4; ni++)
        sf[ni] = __builtin_amdgcn_mfma_f32_16x16x32_bf16(qf[ks], kfr[ni], sf[ni], 0, 0, 0);
    }
    __builtin_amdgcn_s_setprio(0);

    // online softmax with defer-max (skip rescale when tile max is small)
    float tmax[4];
    bool need = false;
#pragma unroll
    for (int r = 0; r < 4; r++) {
      float tm = fmaxf(fmaxf(sf[0][r], sf[1][r]), fmaxf(sf[2][r], sf[3][r]));
#pragma unroll
      for (int off = 1; off < 16; off <<= 1) tm = fmaxf(tm, __shfl_xor(tm, off, 16));
      tm *= ATT_SCALE;
      tmax[r] = tm;
      need = need || (tm > mrun[r] + 8.f);
    }
    if (__any(need)) {
#pragma unroll
      for (int r = 0; r < 4; r++) {
        float mnew = fmaxf(mrun[r], tmax[r]);
        float alpha = __expf(mrun[r] - mnew);
        mrun[r] = mnew;
        lrun[r] *= alpha;
#pragma unroll
        for (int nc = 0; nc < 8; nc++) oacc[nc][r] *= alpha;
      }
    }
#pragma unroll
    for (int r = 0; r < 4; r++) {
      float rs = 0.f;
#pragma unroll
      for (int ni = 0; ni < 4; ni++) {
        float p = __expf(sf[ni][r] * ATT_SCALE - mrun[r]);
        sf[ni][r] = p;
        rs += p;
      }
#pragma unroll
      for (int off = 1; off < 16; off <<= 1) rs += __shfl_xor(rs, off, 16);
      lrun[r] += rs;
    }

    // P -> LDS (per-wave region, 72-elem padded rows: conflict-free)
#pragma unroll
    for (int ni = 0; ni < 4; ni++)
#pragma unroll
      for (int r = 0; r < 4; r++)
        Pl[w * 1152 + (lr * 4 + r) * 72 + ni * 16 + lc] = __float2bfloat16(sf[ni][r]);

    // Own V loads done (V issued before K this iter -> vmcnt(2) leaves K in
    // flight); raw s_barrier publishes ALL waves' V slices without draining K.
    if (it < 31) asm volatile("s_waitcnt vmcnt(2) lgkmcnt(0)" ::: "memory");
    else         asm volatile("s_waitcnt vmcnt(0) lgkmcnt(0)" ::: "memory");
    __builtin_amdgcn_s_barrier();

    // O += P V
    __builtin_amdgcn_s_setprio(1);
#pragma unroll
    for (int ks2 = 0; ks2 < 2; ks2++) {
      bf16x8 pa = *(const bf16x8*)(Pl + w * 1152 + lc * 72 + ks2 * 32 + lr * 8);
#pragma unroll
      for (int nc = 0; nc < 8; nc++) {
        bf16x8 vf = *(const bf16x8*)(Vl + (nc * 16 + lc) * 64 + ((ks2 * 32 + lr * 8) ^ sxz));
        oacc[nc] = __builtin_amdgcn_mfma_f32_16x16x32_bf16(pa, vf, oacc[nc], 0, 0, 0);
      }
    }
    __builtin_amdgcn_s_setprio(0);
    __syncthreads();   // drains+publishes K(t+1); V readers all past PV
  }

  // epilogue: y = O/l + x
#pragma unroll
  for (int r = 0; r < 4; r++) {
    int n = q0 + w * 16 + lr * 4 + r;
    float inv = 1.f / lrun[r];
    size_t base = ((size_t)(b_ * 2048 + n)) * 1024 + h * 128;
#pragma unroll
    for (int nc = 0; nc < 8; nc++) {
      int c = nc * 16 + lc;
      y[base + c] = oacc[nc][r] * inv + x[base + c];
    }
  }
}

// ---------------- launch ----------------
extern "C" void kernel_launch(void* const* d_in, const int* in_sizes, int n_in,
                              void* d_out, int out_size, void* d_ws, size_t ws_size,
                              hipStream_t stream) {
  const float* x   = (const float*)d_in[0];
  const float* lng = (const float*)d_in[1];
  const float* lnb = (const float*)d_in[2];
  const float* w3  = (const float*)d_in[3];
  const float* b3  = (const float*)d_in[4];
  const float* w1  = (const float*)d_in[5];
  const float* b1  = (const float*)d_in[6];
  const float* w2  = (const float*)d_in[7];
  const float* b2  = (const float*)d_in[8];
  float* out = (float*)d_out;

  constexpr size_t M = 8192;
  __hip_bfloat16* w3t  = (__hip_bfloat16*)d_ws;                 // [3072][1024]
  __hip_bfloat16* w1t  = w3t + (size_t)3072 * 1024;             // [4096][1024]
  __hip_bfloat16* w2t  = w1t + (size_t)4096 * 1024;             // [1024][4096]
  __hip_bfloat16* xln  = w2t + (size_t)4096 * 1024;             // [8192][1024] (also y1)
  __hip_bfloat16* qb   = xln + M * 1024;                        // [32][2048][128]
  __hip_bfloat16* kbuf = qb + M * 1024;
  __hip_bfloat16* vtb  = kbuf + M * 1024;
  __hip_bfloat16* hmid = qb;                                    // overlay: [8192][4096]

  k_transpose<1><<<dim3(48, 16), 256, 0, stream>>>(w3, w3t, 1024, 3072);
  k_transpose<0><<<dim3(64, 16), 256, 0, stream>>>(w1, w1t, 1024, 4096);
  k_transpose<0><<<dim3(16, 64), 256, 0, stream>>>(w2, w2t, 4096, 1024);
  k_ln<<<dim3(M), 256, 0, stream>>>(x, lng, lnb, xln);
  k_gemm<0><<<dim3(24, 64), 256, 0, stream>>>(xln, w3t, b3, nullptr, nullptr,
                                              qb, kbuf, vtb, 1024, 3072);
  k_attn<<<dim3(16, 32), 512, 0, stream>>>(qb, kbuf, vtb, x, out);
  k_ln<<<dim3(M), 256, 0, stream>>>(out, lng, lnb, xln);
  k_gemm<1><<<dim3(32, 64), 256, 0, stream>>>(xln, w1t, b1, nullptr, nullptr,
                                              hmid, nullptr, nullptr, 1024, 4096);
  k_gemm<2><<<dim3(8, 64), 256, 0, stream>>>(hmid, w2t, b2, out, out,
                                             nullptr, nullptr, nullptr, 4096, 1024);
}

// Round 8
// 499.600 us; speedup vs baseline: 1.2076x; 1.0810x over previous
//
#include <hip/hip_runtime.h>
#include <hip/hip_bf16.h>
#include <cstdint>

typedef __attribute__((ext_vector_type(8))) __bf16 bf16x8;
typedef __attribute__((ext_vector_type(4))) float f32x4;
typedef unsigned short u16;

#define DEV static __device__ __forceinline__

constexpr float ATT_SCALE = 0.125f;   // 64^-0.5 (module uses dimHead=64)
constexpr float LN_EPS = 1e-3f;

DEV void gload16(const void* g, void* l) {
  __builtin_amdgcn_global_load_lds((__attribute__((address_space(1))) void*)(g),
                                   (__attribute__((address_space(3))) void*)(l),
                                   16, 0, 0);
}

DEV u16 f2b(float f) { __hip_bfloat16 h = __float2bfloat16(f); return __builtin_bit_cast(u16, h); }

// ---------------- weight transpose + convert ----------------
template<int PERM>
__global__ __launch_bounds__(256)
void k_transpose(const float* __restrict__ in, __hip_bfloat16* __restrict__ out,
                 int R, int C) {
  __shared__ float t[64][65];
  int d0 = blockIdx.x * 64, k0 = blockIdx.y * 64;
  int tid = threadIdx.x;
  int c64 = tid & 63, r4 = tid >> 6;
#pragma unroll
  for (int i = 0; i < 16; i++) {
    int kr = i * 4 + r4;
    t[c64][kr] = in[(size_t)(k0 + kr) * C + d0 + c64];
  }
  __syncthreads();
#pragma unroll
  for (int i = 0; i < 16; i++) {
    int dr = i * 4 + r4;
    int d = d0 + dr;
    int jp = PERM ? ((d % 3) * 1024 + ((d / 3) & 7) * 128 + (d / 24)) : d;
    out[(size_t)jp * R + k0 + c64] = __float2bfloat16(t[dr][c64]);
  }
}

// ---------------- LayerNorm (f32 in -> bf16 out) ----------------
__global__ __launch_bounds__(256)
void k_ln(const float* __restrict__ in, const float* __restrict__ g,
          const float* __restrict__ b, __hip_bfloat16* __restrict__ out) {
  int row = blockIdx.x, tid = threadIdx.x;
  const float4* in4 = (const float4*)(in + (size_t)row * 1024);
  float4 v = in4[tid];
  float s = v.x + v.y + v.z + v.w;
  float ss = v.x * v.x + v.y * v.y + v.z * v.z + v.w * v.w;
#pragma unroll
  for (int off = 32; off; off >>= 1) { s += __shfl_down(s, off); ss += __shfl_down(ss, off); }
  __shared__ float red[8];
  int w = tid >> 6, lane = tid & 63;
  if (lane == 0) { red[w] = s; red[4 + w] = ss; }
  __syncthreads();
  if (tid == 0) {
    float S = red[0] + red[1] + red[2] + red[3];
    float SS = red[4] + red[5] + red[6] + red[7];
    float mu = S * (1.f / 1024.f);
    float var = SS * (1.f / 1024.f) - mu * mu;
    red[0] = mu; red[1] = rsqrtf(var + LN_EPS);
  }
  __syncthreads();
  float mu = red[0], rs = red[1];
  int c = tid * 4;
  ushort4 o;
  o.x = f2b((v.x - mu) * rs * g[c + 0] + b[c + 0]);
  o.y = f2b((v.y - mu) * rs * g[c + 1] + b[c + 1]);
  o.z = f2b((v.z - mu) * rs * g[c + 2] + b[c + 2]);
  o.w = f2b((v.w - mu) * rs * g[c + 3] + b[c + 3]);
  ((ushort4*)((u16*)out + (size_t)row * 1024))[tid] = o;
}

// ---------------- GEMM: C[M,N] = A[M,K] * Bt[N,K]^T -------------------------
// 2-phase double-buffer (T3-min): STAGE(t+1) issued BEFORE compute of tile t;
// single __syncthreads per K-step (vmcnt(0) drain lands a full phase after
// issue). LDS 32.8KB. MODE 0: qkv scatter; 1: relu->bf16; 2: +resid->f32.
template<int MODE>
__global__ __launch_bounds__(256, 2)
void k_gemm(const __hip_bfloat16* __restrict__ A,
            const __hip_bfloat16* __restrict__ Bt,
            const float* __restrict__ bias,
            const float* __restrict__ resid,
            float* __restrict__ outF,
            __hip_bfloat16* __restrict__ outQ,
            __hip_bfloat16* __restrict__ outK,
            __hip_bfloat16* __restrict__ outV,
            int K, int Nout) {
  __shared__ alignas(16) __hip_bfloat16 lds[2][2 * 128 * 32];  // [buf][A|B]
  int tid = threadIdx.x, w = tid >> 6, lane = tid & 63;
  int wr = w >> 1, wc = w & 1;
  int lr = lane >> 4, lc = lane & 15;
  int m0 = blockIdx.y * 128, n0 = blockIdx.x * 128;
  f32x4 acc[4][4] = {};
  const __hip_bfloat16* aG = A + (size_t)(m0 + (tid >> 2)) * K + (tid & 3) * 8;
  const __hip_bfloat16* bG = Bt + (size_t)(n0 + (tid >> 2)) * K + (tid & 3) * 8;
  const size_t K64 = (size_t)64 * K;
  int NT = K >> 5;

  auto STAGE = [&](int t, int buf) {
    char* s = (char*)(&lds[buf][0]) + w * 1024;
    const __hip_bfloat16* ap = aG + t * 32;
    gload16(ap, s);
    gload16(ap + K64, s + 4096);
    const __hip_bfloat16* bp = bG + t * 32;
    gload16(bp, s + 8192);
    gload16(bp + K64, s + 12288);
  };

  STAGE(0, 0);
  __syncthreads();
  int cur = 0;
  for (int t = 0; t < NT; ++t) {
    if (t + 1 < NT) STAGE(t + 1, cur ^ 1);
    const __hip_bfloat16* Asm = &lds[cur][0];
    const __hip_bfloat16* Bsm = &lds[cur][128 * 32];
    bf16x8 af[4], bfr[4];
#pragma unroll
    for (int mi = 0; mi < 4; mi++)
      af[mi] = *(const bf16x8*)(Asm + (wr * 64 + mi * 16 + lc) * 32 + lr * 8);
#pragma unroll
    for (int ni = 0; ni < 4; ni++)
      bfr[ni] = *(const bf16x8*)(Bsm + (wc * 64 + ni * 16 + lc) * 32 + lr * 8);
    __builtin_amdgcn_s_setprio(1);
#pragma unroll
    for (int mi = 0; mi < 4; mi++)
#pragma unroll
      for (int ni = 0; ni < 4; ni++)
        acc[mi][ni] = __builtin_amdgcn_mfma_f32_16x16x32_bf16(af[mi], bfr[ni], acc[mi][ni], 0, 0, 0);
    __builtin_amdgcn_s_setprio(0);
    __syncthreads();   // drains STAGE(t+1) (issued a full phase ago) + publishes
    cur ^= 1;
  }

#pragma unroll
  for (int mi = 0; mi < 4; mi++) {
#pragma unroll
    for (int ni = 0; ni < 4; ni++) {
      int jp = n0 + wc * 64 + ni * 16 + lc;
#pragma unroll
      for (int r = 0; r < 4; r++) {
        int m = m0 + wr * 64 + mi * 16 + lr * 4 + r;
        float v = acc[mi][ni][r];
        if (MODE == 0) {
          int i = jp >> 10, h = (jp >> 7) & 7, c = jp & 127;
          v += bias[c * 24 + h * 3 + i];
          v = fmaxf(v, 0.f);
          __hip_bfloat16 bv = __float2bfloat16(v);
          int b_ = m >> 11, n = m & 2047;
          size_t bh = (size_t)(b_ * 8 + h);
          if (i == 0)      outQ[(bh * 2048 + n) * 128 + c] = bv;
          else if (i == 1) outK[(bh * 2048 + n) * 128 + c] = bv;
          else             outV[(bh * 128 + c) * 2048 + n] = bv;
        } else if (MODE == 1) {
          v += bias[jp];
          v = fmaxf(v, 0.f);
          outQ[(size_t)m * Nout + jp] = __float2bfloat16(v);
        } else {
          v += bias[jp] + resid[(size_t)m * Nout + jp];
          outF[(size_t)m * Nout + jp] = v;
        }
      }
    }
  }
}

// ---------------- flash attention + residual ----------------
// 512 thr (8 waves), QBLK=128, KVBLK=64.  K dbuf, V single-buffer (counted
// vmcnt(2) + raw s_barrier publishes V; K prefetch stays in flight).
// Softmax: lazy max (lane-local trigger, full reduce only when fired) and
// row-sums via ones-column MFMA on the PV A-fragment (no sum shuffles).
__global__ __launch_bounds__(512, 4)
void k_attn(const __hip_bfloat16* __restrict__ qb,
            const __hip_bfloat16* __restrict__ kb,
            const __hip_bfloat16* __restrict__ vtb,
            const float* __restrict__ x,
            float* __restrict__ y) {
  __shared__ alignas(16) __hip_bfloat16 Kl[2][64 * 128];   // [kv][c] swizzled
  __shared__ alignas(16) __hip_bfloat16 Vl[128 * 64];      // [c][kv] swizzled
  __shared__ alignas(16) __hip_bfloat16 Pl[8 * 16 * 72];
  int tid = threadIdx.x, w = tid >> 6, lane = tid & 63;
  int lr = lane >> 4, lc = lane & 15;
  int sxz = (lc & 7) << 3;                 // read-side XOR (elems)
  int qt = blockIdx.x, bh = blockIdx.y;
  int b_ = bh >> 3, h = bh & 7;
  int q0 = qt * 128;
  size_t bhN = (size_t)bh * 2048;

  const u16 one16 = 0x3F80;                // bf16 1.0
  const __bf16 oneb = __builtin_bit_cast(__bf16, one16);
  const bf16x8 vones = {oneb, oneb, oneb, oneb, oneb, oneb, oneb, oneb};

  // Q fragment: wave owns q rows [q0 + w*16, +16)
  bf16x8 qf[4];
#pragma unroll
  for (int ks = 0; ks < 4; ks++)
    qf[ks] = *(const bf16x8*)(qb + (bhN + q0 + w * 16 + lc) * 128 + ks * 32 + lr * 8);

  f32x4 oacc[8] = {};
  f32x4 osum = {};                          // osum[r] = running row-sum of P
  float mrun[4];
#pragma unroll
  for (int r = 0; r < 4; r++) mrun[r] = -1e30f;

  // staging addresses: linear LDS dest, source column pre-swizzled by row&7
  int krow = tid >> 4;                                   // 0..31 (+p*32)
  int kcol = ((tid & 15) * 8) ^ ((krow & 7) << 3);
  const __hip_bfloat16* kG = kb + (bhN + krow) * 128 + kcol;
  int vrow = tid >> 3;                                   // 0..63 (+p*64)
  int vcol = ((tid & 7) * 8) ^ ((vrow & 7) << 3);
  const __hip_bfloat16* vG = vtb + ((size_t)bh * 128 + vrow) * 2048 + vcol;

  auto STAGE_K = [&](int kv0, int buf) {
    char* kB = (char*)(&Kl[buf][0]) + w * 1024;
#pragma unroll
    for (int p = 0; p < 2; p++)
      gload16(kG + (size_t)(kv0 + p * 32) * 128, kB + p * 8192);
  };
  auto STAGE_V = [&](int kv0) {
    char* vB = (char*)(&Vl[0]) + w * 1024;
#pragma unroll
    for (int p = 0; p < 2; p++)
      gload16(vG + kv0 + (size_t)p * 64 * 2048, vB + p * 8192);
  };

  STAGE_V(0);
  STAGE_K(0, 0);
  asm volatile("s_waitcnt vmcnt(0)" ::: "memory");
  __syncthreads();

  for (int it = 0; it < 32; ++it) {
    int buf = it & 1;
    if (it > 0) STAGE_V(it * 64);            // into single V buffer (post-barrier legal)
    if (it < 31) STAGE_K((it + 1) * 64, buf ^ 1);
    const __hip_bfloat16* Kb = &Kl[buf][0];

    // S = Q K^T : 16 q rows x 64 kv cols per wave
    f32x4 sf[4] = {};
    __builtin_amdgcn_s_setprio(1);
#pragma unroll
    for (int ks = 0; ks < 4; ks++) {
      bf16x8 kfr[4];
#pragma unroll
      for (int ni = 0; ni < 4; ni++)
        kfr[ni] = *(const bf16x8*)(Kb + (ni * 16 + lc) * 128 + ((ks * 32 + lr * 8) ^ sxz));
#pragma unroll
      for (int ni = 0; ni < 4; ni++)
        sf[ni] = __builtin_amdgcn_mfma_f32_16x16x32_bf16(qf[ks], kfr[ni], sf[ni], 0, 0, 0);
    }
    __builtin_amdgcn_s_setprio(0);

    // lazy max: lane-local trigger, full reduce + rescale only when fired
    float lmax[4];
    bool need = false;
#pragma unroll
    for (int r = 0; r < 4; r++) {
      lmax[r] = fmaxf(fmaxf(sf[0][r], sf[1][r]), fmaxf(sf[2][r], sf[3][r]));
      need = need || (lmax[r] * ATT_SCALE > mrun[r] + 8.f);
    }
    if (__any(need)) {
#pragma unroll
      for (int r = 0; r < 4; r++) {
        float tm = lmax[r];
#pragma unroll
        for (int off = 1; off < 16; off <<= 1) tm = fmaxf(tm, __shfl_xor(tm, off, 16));
        float mnew = fmaxf(mrun[r], tm * ATT_SCALE);
        float alpha = __expf(mrun[r] - mnew);
        mrun[r] = mnew;
        osum[r] *= alpha;
#pragma unroll
        for (int nc = 0; nc < 8; nc++) oacc[nc][r] *= alpha;
      }
    }
    // P = exp(S*scale - m); no sum pass (ones-column MFMA below)
#pragma unroll
    for (int r = 0; r < 4; r++)
#pragma unroll
      for (int ni = 0; ni < 4; ni++)
        sf[ni][r] = __expf(sf[ni][r] * ATT_SCALE - mrun[r]);

    // P -> LDS (per-wave region, 72-elem padded rows: conflict-free)
#pragma unroll
    for (int ni = 0; ni < 4; ni++)
#pragma unroll
      for (int r = 0; r < 4; r++)
        Pl[w * 1152 + (lr * 4 + r) * 72 + ni * 16 + lc] = __float2bfloat16(sf[ni][r]);

    // Own V loads done (V issued before K this iter -> vmcnt(2) leaves K in
    // flight); raw s_barrier publishes ALL waves' V slices without draining K.
    if (it < 31) asm volatile("s_waitcnt vmcnt(2) lgkmcnt(0)" ::: "memory");
    else         asm volatile("s_waitcnt vmcnt(0) lgkmcnt(0)" ::: "memory");
    __builtin_amdgcn_s_barrier();

    // O += P V ; row-sum += P * ones (same A-fragment)
    __builtin_amdgcn_s_setprio(1);
#pragma unroll
    for (int ks2 = 0; ks2 < 2; ks2++) {
      bf16x8 pa = *(const bf16x8*)(Pl + w * 1152 + lc * 72 + ks2 * 32 + lr * 8);
      osum = __builtin_amdgcn_mfma_f32_16x16x32_bf16(pa, vones, osum, 0, 0, 0);
#pragma unroll
      for (int nc = 0; nc < 8; nc++) {
        bf16x8 vf = *(const bf16x8*)(Vl + (nc * 16 + lc) * 64 + ((ks2 * 32 + lr * 8) ^ sxz));
        oacc[nc] = __builtin_amdgcn_mfma_f32_16x16x32_bf16(pa, vf, oacc[nc], 0, 0, 0);
      }
    }
    __builtin_amdgcn_s_setprio(0);
    __syncthreads();   // drains+publishes K(t+1); V readers all past PV
  }

  // epilogue: y = O/l + x   (l = osum via ones-column MFMA)
#pragma unroll
  for (int r = 0; r < 4; r++) {
    int n = q0 + w * 16 + lr * 4 + r;
    float inv = 1.f / osum[r];
    size_t base = ((size_t)(b_ * 2048 + n)) * 1024 + h * 128;
#pragma unroll
    for (int nc = 0; nc < 8; nc++) {
      int c = nc * 16 + lc;
      y[base + c] = oacc[nc][r] * inv + x[base + c];
    }
  }
}

// ---------------- launch ----------------
extern "C" void kernel_launch(void* const* d_in, const int* in_sizes, int n_in,
                              void* d_out, int out_size, void* d_ws, size_t ws_size,
                              hipStream_t stream) {
  const float* x   = (const float*)d_in[0];
  const float* lng = (const float*)d_in[1];
  const float* lnb = (const float*)d_in[2];
  const float* w3  = (const float*)d_in[3];
  const float* b3  = (const float*)d_in[4];
  const float* w1  = (const float*)d_in[5];
  const float* b1  = (const float*)d_in[6];
  const float* w2  = (const float*)d_in[7];
  const float* b2  = (const float*)d_in[8];
  float* out = (float*)d_out;

  constexpr size_t M = 8192;
  __hip_bfloat16* w3t  = (__hip_bfloat16*)d_ws;                 // [3072][1024]
  __hip_bfloat16* w1t  = w3t + (size_t)3072 * 1024;             // [4096][1024]
  __hip_bfloat16* w2t  = w1t + (size_t)4096 * 1024;             // [1024][4096]
  __hip_bfloat16* xln  = w2t + (size_t)4096 * 1024;             // [8192][1024] (also y1)
  __hip_bfloat16* qb   = xln + M * 1024;                        // [32][2048][128]
  __hip_bfloat16* kbuf = qb + M * 1024;
  __hip_bfloat16* vtb  = kbuf + M * 1024;
  __hip_bfloat16* hmid = qb;                                    // overlay: [8192][4096]

  k_transpose<1><<<dim3(48, 16), 256, 0, stream>>>(w3, w3t, 1024, 3072);
  k_transpose<0><<<dim3(64, 16), 256, 0, stream>>>(w1, w1t, 1024, 4096);
  k_transpose<0><<<dim3(16, 64), 256, 0, stream>>>(w2, w2t, 4096, 1024);
  k_ln<<<dim3(M), 256, 0, stream>>>(x, lng, lnb, xln);
  k_gemm<0><<<dim3(24, 64), 256, 0, stream>>>(xln, w3t, b3, nullptr, nullptr,
                                              qb, kbuf, vtb, 1024, 3072);
  k_attn<<<dim3(16, 32), 512, 0, stream>>>(qb, kbuf, vtb, x, out);
  k_ln<<<dim3(M), 256, 0, stream>>>(out, lng, lnb, xln);
  k_gemm<1><<<dim3(32, 64), 256, 0, stream>>>(xln, w1t, b1, nullptr, nullptr,
                                              hmid, nullptr, nullptr, 1024, 4096);
  k_gemm<2><<<dim3(8, 64), 256, 0, stream>>>(hmid, w2t, b2, out, out,
                                             nullptr, nullptr, nullptr, 4096, 1024);
}